// Round 1
// baseline (337.976 us; speedup 1.0000x reference)
//
#include <hip/hip_runtime.h>
#include <stdint.h>
#include <stddef.h>

#define BB 32
#define PP 9045
#define FF 750
#define MM (BB*PP)        // 289440 rows
#define NT16 (MM/16)      // 18090 16-row tiles (exact)

typedef float  f32x4  __attribute__((ext_vector_type(4)));
typedef short  s16x8  __attribute__((ext_vector_type(8)));
typedef unsigned int u32x4v __attribute__((ext_vector_type(4)));

__device__ __forceinline__ unsigned rne_bf16(float f){
    unsigned u = __builtin_bit_cast(unsigned, f);
    return (u + 0x7fffu + ((u >> 16) & 1u)) >> 16;   // round-to-nearest-even
}
__device__ __forceinline__ unsigned pack2(float lo, float hi){
    return rne_bf16(lo) | (rne_bf16(hi) << 16);
}
__device__ __forceinline__ float tanh_fast(float v){
    return 1.f - 2.f / (1.f + __expf(2.f * v));
}

// ---------------- K0: pre-pack sw1 (750x32 f32) into MFMA B-fragment layout -----------
// Fragment for v_mfma_f32_16x16x32_bf16, B[k][col]: lane holds col=lane&15,
// k = 8*(lane>>4)+e, e=0..7 (8 bf16 = one dwordx4). Index: (s*2+nt)*64 + lane.
__global__ void k_w1f(const float* __restrict__ sw1, u32x4v* __restrict__ w1f){
    int t = blockIdx.x * blockDim.x + threadIdx.x;   // 0..3071
    if (t >= 24*2*64) return;
    int lane = t & 63, nt = (t >> 6) & 1, s = t >> 7;
    int col = nt*16 + (lane & 15);
    int kb  = s*32 + ((lane >> 4) << 3);
    float v[8];
    #pragma unroll
    for (int e = 0; e < 8; ++e){ int k = kb + e; v[e] = (k < FF) ? sw1[k*32 + col] : 0.f; }
    u32x4v o;
    o.x = pack2(v[0],v[1]); o.y = pack2(v[2],v[3]);
    o.z = pack2(v[4],v[5]); o.w = pack2(v[6],v[7]);
    w1f[t] = o;
}

// ---------------- KA: fused similarity MLP (750->32->16->8->1), one wave per 16 rows ---
__global__ __launch_bounds__(256) void k_sim(
    const float* __restrict__ x, const u32x4v* __restrict__ w1f,
    const float* __restrict__ sb1,
    const float* __restrict__ sw2, const float* __restrict__ sb2,
    const float* __restrict__ sw3, const float* __restrict__ sb3,
    const float* __restrict__ sw4, const float* __restrict__ sb4,
    float* __restrict__ simT)
{
    __shared__ __align__(16) unsigned short h1buf[4][16*40]; // per-wave 16x32 bf16, stride 40
    __shared__ __align__(16) unsigned short h2buf[4][16*40];
    const int wid  = threadIdx.x >> 6;
    const int lane = threadIdx.x & 63;
    // zero h2 region (k=16..31 must read as 0 for the padded layer-3 MFMA)
    for (int i = lane; i < 16*40; i += 64) h2buf[wid][i] = 0;
    const int tile = blockIdx.x*4 + wid;
    if (tile >= NT16) return;
    const int g = lane >> 4;     // k-group
    const int c = lane & 15;     // row (A) / col (B,D)
    const int r0 = tile << 4;
    const int row = r0 + c;

    // per-lane constant fragments for layers 2/3 + biases
    u32x4v t2, t3;
    {
        float v[8];
        #pragma unroll
        for (int e = 0; e < 8; ++e) v[e] = sw2[(8*g+e)*16 + c];          // sw2: [32][16]
        t2.x = pack2(v[0],v[1]); t2.y = pack2(v[2],v[3]);
        t2.z = pack2(v[4],v[5]); t2.w = pack2(v[6],v[7]);
        #pragma unroll
        for (int e = 0; e < 8; ++e){
            int k = 8*g+e;
            v[e] = (k < 16 && c < 8) ? sw3[k*8 + c] : 0.f;               // sw3: [16][8], zero-pad
        }
        t3.x = pack2(v[0],v[1]); t3.y = pack2(v[2],v[3]);
        t3.z = pack2(v[4],v[5]); t3.w = pack2(v[6],v[7]);
    }
    const s16x8 w2f = __builtin_bit_cast(s16x8, t2);
    const s16x8 w3f = __builtin_bit_cast(s16x8, t3);
    const float w4c  = (c < 8) ? sw4[c] : 0.f;
    const float sb4v = sb4[0];
    const float b2c  = sb2[c];
    const float b3c  = (c < 8) ? sb3[c] : 0.f;

    f32x4 acc0, acc1;
    { float b0 = sb1[c], b1 = sb1[16+c];
      acc0 = (f32x4){b0,b0,b0,b0}; acc1 = (f32x4){b1,b1,b1,b1}; }

    // A loaded straight from global: lane needs x[row][32s+8g .. +7] (8B-aligned float2s)
    const float2* xr = reinterpret_cast<const float2*>(x + (size_t)row*FF) + g*4;
    const u32x4v* wf = w1f + lane;

    #pragma unroll 4
    for (int s = 0; s < 23; ++s){
        float2 p0 = xr[16*s+0], p1 = xr[16*s+1], p2 = xr[16*s+2], p3 = xr[16*s+3];
        u32x4v a;
        a.x = pack2(p0.x,p0.y); a.y = pack2(p1.x,p1.y);
        a.z = pack2(p2.x,p2.y); a.w = pack2(p3.x,p3.y);
        s16x8 av  = __builtin_bit_cast(s16x8, a);
        s16x8 bv0 = __builtin_bit_cast(s16x8, wf[(2*s+0)*64]);
        s16x8 bv1 = __builtin_bit_cast(s16x8, wf[(2*s+1)*64]);
        acc0 = __builtin_amdgcn_mfma_f32_16x16x32_bf16(av, bv0, acc0, 0,0,0);
        acc1 = __builtin_amdgcn_mfma_f32_16x16x32_bf16(av, bv1, acc1, 0,0,0);
    }
    {   // tail k-step s=23 (k=736..749, masked)
        int kb = 736 + g*8;
        float v[8];
        #pragma unroll
        for (int e = 0; e < 8; ++e){
            int k = kb + e;
            v[e] = (k < FF) ? x[(size_t)row*FF + k] : 0.f;
        }
        u32x4v a;
        a.x = pack2(v[0],v[1]); a.y = pack2(v[2],v[3]);
        a.z = pack2(v[4],v[5]); a.w = pack2(v[6],v[7]);
        s16x8 av  = __builtin_bit_cast(s16x8, a);
        s16x8 bv0 = __builtin_bit_cast(s16x8, wf[46*64]);
        s16x8 bv1 = __builtin_bit_cast(s16x8, wf[47*64]);
        acc0 = __builtin_amdgcn_mfma_f32_16x16x32_bf16(av, bv0, acc0, 0,0,0);
        acc1 = __builtin_amdgcn_mfma_f32_16x16x32_bf16(av, bv1, acc1, 0,0,0);
    }

    // h1 = relu(acc) -> LDS in A-frag-ready layout (D: row=4g+j, col=c)
    unsigned short* h1 = h1buf[wid];
    #pragma unroll
    for (int j = 0; j < 4; ++j){
        h1[(4*g+j)*40 + c]      = (unsigned short)rne_bf16(fmaxf(acc0[j], 0.f));
        h1[(4*g+j)*40 + 16 + c] = (unsigned short)rne_bf16(fmaxf(acc1[j], 0.f));
    }
    asm volatile("s_waitcnt lgkmcnt(0)" ::: "memory");   // same-wave LDS RAW
    s16x8 a2 = *reinterpret_cast<const s16x8*>(&h1[c*40 + 8*g]);
    f32x4 c2i = {b2c,b2c,b2c,b2c};
    f32x4 d2 = __builtin_amdgcn_mfma_f32_16x16x32_bf16(a2, w2f, c2i, 0,0,0);

    unsigned short* h2 = h2buf[wid];
    #pragma unroll
    for (int j = 0; j < 4; ++j)
        h2[(4*g+j)*40 + c] = (unsigned short)rne_bf16(fmaxf(d2[j], 0.f));
    asm volatile("s_waitcnt lgkmcnt(0)" ::: "memory");
    s16x8 a3 = *reinterpret_cast<const s16x8*>(&h2[c*40 + 8*g]);
    f32x4 c3i = {b3c,b3c,b3c,b3c};
    f32x4 d3 = __builtin_amdgcn_mfma_f32_16x16x32_bf16(a3, w3f, c3i, 0,0,0);

    // layer 4: per-row dot over 8 cols (cols 8..15 are exact zeros), 16-lane butterfly
    #pragma unroll
    for (int j = 0; j < 4; ++j){
        float t = fmaxf(d3[j], 0.f) * w4c;
        t += __shfl_xor(t, 1);
        t += __shfl_xor(t, 2);
        t += __shfl_xor(t, 4);
        t += __shfl_xor(t, 8);
        if (c == 0){
            int grow = r0 + 4*g + j;
            int b = grow / PP;
            int p = grow - b*PP;
            simT[p*32 + b] = tanh_fast(t + sb4v);   // transposed: simT[p][32 subjects]
        }
    }
}

// ---------------- KB1: c1 = sim @ cw1 (K=9045 split 32-ways, fp32 atomic partials) -----
__global__ __launch_bounds__(256) void k_c1(
    const float* __restrict__ simT, const float* __restrict__ cw1,
    float* __restrict__ c1)
{
    const int nb = blockIdx.x & 7;        // 8 n-blocks of 128
    const int ks = blockIdx.x >> 3;       // 32 k-splits of 283
    const int t  = threadIdx.x;
    const int n  = nb*128 + (t & 127);
    const int kh = t >> 7;
    const int k0 = ks*283;
    const int k1 = (k0 + 283 < PP) ? k0 + 283 : PP;
    float acc[BB];
    #pragma unroll
    for (int b = 0; b < BB; ++b) acc[b] = 0.f;
    for (int k = k0 + kh; k < k1; k += 2){
        float w = cw1[(size_t)k*1024 + n];
        const float* sp = simT + k*32;    // wave-uniform -> s_loads
        #pragma unroll
        for (int b = 0; b < BB; ++b) acc[b] = fmaf(sp[b], w, acc[b]);
    }
    #pragma unroll
    for (int b = 0; b < BB; ++b) atomicAdd(c1 + b*1024 + n, acc[b]);
}

// ---------------- KB2: 1024->256->64->3 + log_softmax, one block per subject ----------
__global__ __launch_bounds__(256) void k_cls(
    const float* __restrict__ c1raw, const float* __restrict__ cb1,
    const float* __restrict__ cw2,  const float* __restrict__ cb2,
    const float* __restrict__ cw3,  const float* __restrict__ cb3,
    const float* __restrict__ cw4,  const float* __restrict__ cb4,
    float* __restrict__ out)
{
    __shared__ __align__(16) float c1s[1024];
    __shared__ float c2s[256];
    __shared__ float c3s[64];
    __shared__ float lgs[3];
    const int b = blockIdx.x, t = threadIdx.x;
    #pragma unroll
    for (int i = 0; i < 4; ++i){
        int n = i*256 + t;
        c1s[n] = fmaxf(c1raw[b*1024 + n] + cb1[n], 0.f);
    }
    __syncthreads();
    {
        float a = cb2[t];
        for (int k = 0; k < 1024; k += 4){
            float4 cv = *reinterpret_cast<const float4*>(&c1s[k]);
            a = fmaf(cv.x, cw2[(k+0)*256 + t], a);
            a = fmaf(cv.y, cw2[(k+1)*256 + t], a);
            a = fmaf(cv.z, cw2[(k+2)*256 + t], a);
            a = fmaf(cv.w, cw2[(k+3)*256 + t], a);
        }
        c2s[t] = fmaxf(a, 0.f);
    }
    __syncthreads();
    if (t < 64){
        float a = cb3[t];
        for (int k = 0; k < 256; ++k) a = fmaf(c2s[k], cw3[k*64 + t], a);
        c3s[t] = fmaxf(a, 0.f);
    }
    __syncthreads();
    if (t < 3){
        float a = cb4[t];
        for (int k = 0; k < 64; ++k) a = fmaf(c3s[k], cw4[k*3 + t], a);
        lgs[t] = a;
    }
    __syncthreads();
    if (t < 3){
        float m = fmaxf(fmaxf(lgs[0], lgs[1]), lgs[2]);
        float s = __expf(lgs[0]-m) + __expf(lgs[1]-m) + __expf(lgs[2]-m);
        out[b*3 + t] = lgs[t] - m - __logf(s);
    }
}

extern "C" void kernel_launch(void* const* d_in, const int* in_sizes, int n_in,
                              void* d_out, int out_size, void* d_ws, size_t ws_size,
                              hipStream_t stream) {
    const float* x   = (const float*)d_in[0];
    const float* sw1 = (const float*)d_in[1];
    const float* sb1 = (const float*)d_in[2];
    const float* sw2 = (const float*)d_in[3];
    const float* sb2 = (const float*)d_in[4];
    const float* sw3 = (const float*)d_in[5];
    const float* sb3 = (const float*)d_in[6];
    const float* sw4 = (const float*)d_in[7];
    const float* sb4 = (const float*)d_in[8];
    const float* cw1 = (const float*)d_in[9];
    const float* cb1 = (const float*)d_in[10];
    const float* cw2 = (const float*)d_in[11];
    const float* cb2 = (const float*)d_in[12];
    const float* cw3 = (const float*)d_in[13];
    const float* cb3 = (const float*)d_in[14];
    const float* cw4 = (const float*)d_in[15];
    const float* cb4 = (const float*)d_in[16];

    char* ws = (char*)d_ws;
    u32x4v* w1f = (u32x4v*)ws;                         // 48 KB fragment-packed sw1
    float* simT = (float*)(ws + (64<<10));             // 9045*32 f32 = 1.13 MB
    float* c1   = (float*)(ws + (64<<10) + 1310720);   // 32*1024 f32 = 128 KB

    hipMemsetAsync(c1, 0, BB*1024*sizeof(float), stream);
    k_w1f<<<12, 256, 0, stream>>>(sw1, w1f);
    k_sim<<<(NT16 + 3)/4, 256, 0, stream>>>(x, w1f, sb1, sw2, sb2, sw3, sb3,
                                            sw4, sb4, simT);
    k_c1 <<<256, 256, 0, stream>>>(simT, cw1, c1);
    k_cls<<<BB, 256, 0, stream>>>(c1, cb1, cw2, cb2, cw3, cb3, cw4, cb4,
                                  (float*)d_out);
}